// Round 6
// baseline (57.536 us; speedup 1.0000x reference)
//
#include <hip/hip_runtime.h>

#define B_    1024
#define NIN_  128
#define NOUT_ 128
#define N_    512
#define EPS_  1e-5f
#define NPART 16          // stat-reduction partial blocks

// k1: masked reduce over n + fused 128x128 linear
// grid = B_, block = 512 (8 waves). Wave w owns channels {w, w+8, ..., w+120}.
// Loads for 8 channels stream back-to-back before any cross-lane reduce;
// the 8 butterflies then run as independent chains (ILP), not serialized
// per-channel behind each load batch.
__global__ __launch_bounds__(512) void k1_maskreduce_linear(
    const int* __restrict__ A, const float* __restrict__ x,
    const float* __restrict__ W, const float* __restrict__ bias,
    const int* __restrict__ dil_p, float* __restrict__ h,
    float* __restrict__ outA)
{
    __shared__ float m[N_];
    __shared__ float s[NIN_];
    const int b = blockIdx.x;
    const int t = threadIdx.x;
    const int dil = *dil_p;

    // Load A row, build mask in LDS, and emit output 0 (A as float)
    const int* Arow = A + (size_t)b * N_;
    float* oA = outA + (size_t)b * N_;
    {
        int n = t;               // 512 threads, N_=512: one element each
        int a = Arow[n];
        m[n] = (a == dil || a == -1) ? 1.0f : 0.0f;
        oA[n] = (float)a;
    }
    __syncthreads();

    const int wave = t >> 6;
    const int lane = t & 63;

    // Per-lane mask registers: lane l covers n in [4l,4l+4) and [256+4l,256+4l+4)
    float mA[4], mB[4];
    #pragma unroll
    for (int j = 0; j < 4; ++j) {
        mA[j] = m[lane * 4 + j];
        mB[j] = m[256 + lane * 4 + j];
    }

    const float* base = x + (size_t)b * NIN_ * N_;

    #pragma unroll
    for (int c = 0; c < 2; ++c) {
        // Streaming phase: 16 contiguous 1KB wave-loads, FMA only (no cross-lane)
        float acc[8];
        #pragma unroll
        for (int j = 0; j < 8; ++j) {
            const int ch = wave + 8 * (8 * c + j);
            const float* row = base + (size_t)ch * N_;
            float4 v0 = *(const float4*)(row + lane * 4);
            float4 v1 = *(const float4*)(row + 256 + lane * 4);
            acc[j] = v0.x * mA[0] + v0.y * mA[1] + v0.z * mA[2] + v0.w * mA[3]
                   + v1.x * mB[0] + v1.y * mB[1] + v1.z * mB[2] + v1.w * mB[3];
        }
        // Reduce phase: 8 independent butterflies, 6 steps, 8-wide ILP per step
        #pragma unroll
        for (int off = 32; off > 0; off >>= 1) {
            #pragma unroll
            for (int j = 0; j < 8; ++j)
                acc[j] += __shfl_xor(acc[j], off, 64);
        }
        if (lane == 0) {
            #pragma unroll
            for (int j = 0; j < 8; ++j)
                s[wave + 8 * (8 * c + j)] = acc[j];
        }
    }
    __syncthreads();

    // h[b,o] = bias[o] + sum_i W[o,i] * s[i]   (threads 0..127; W L2-resident)
    if (t < NOUT_) {
        const float* Wr = W + (size_t)t * NIN_;
        float acc = bias[t];
        #pragma unroll 8
        for (int i = 0; i < NIN_; ++i) acc += Wr[i] * s[i];
        h[(size_t)b * NOUT_ + t] = acc;
    }
}

// k2: coalesced two-level batch-stat partials.
// grid = NPART, block = 256. Block j reduces h[64j .. 64j+64, :].
__global__ __launch_bounds__(256) void k2_partial(
    const float* __restrict__ h, float* __restrict__ pS, float* __restrict__ pQ)
{
    const int j = blockIdx.x;
    const int t = threadIdx.x;
    const int o = t & (NOUT_ - 1);
    const int half = t >> 7;             // 0 or 1: rows [0,32) or [32,64)
    const float* base = h + ((size_t)j * 64 + half * 32) * NOUT_;
    float s = 0.f, q = 0.f;
    #pragma unroll 8
    for (int r = 0; r < 32; ++r) {
        float v = base[(size_t)r * NOUT_ + o];   // consecutive t -> consecutive addr
        s += v; q += v * v;
    }
    __shared__ float ls[2][NOUT_], lq[2][NOUT_];
    ls[half][o] = s; lq[half][o] = q;
    __syncthreads();
    if (t < NOUT_) {
        pS[j * NOUT_ + t] = ls[0][t] + ls[1][t];
        pQ[j * NOUT_ + t] = lq[0][t] + lq[1][t];
    }
}

// k3: stats from partials (L2-hot) + normalize + ReLU
// grid = B_*NOUT_/256, block = 256
__global__ __launch_bounds__(256) void k3_norm(
    const float* __restrict__ h, const float* __restrict__ pS,
    const float* __restrict__ pQ, const float* __restrict__ gamma,
    const float* __restrict__ beta, float* __restrict__ outF)
{
    const int idx = blockIdx.x * 256 + threadIdx.x;
    const int o = idx & (NOUT_ - 1);
    float S = 0.f, Q = 0.f;
    #pragma unroll
    for (int j = 0; j < NPART; ++j) {
        S += pS[j * NOUT_ + o];
        Q += pQ[j * NOUT_ + o];
    }
    float mean = S * (1.0f / B_);
    float var  = Q * (1.0f / B_) - mean * mean;   // biased, training mode
    float sc   = gamma[o] * rsqrtf(var + EPS_);
    float sh   = beta[o] - mean * sc;
    float v = fmaf(h[idx], sc, sh);
    outF[idx] = fmaxf(v, 0.0f);
}

extern "C" void kernel_launch(void* const* d_in, const int* in_sizes, int n_in,
                              void* d_out, int out_size, void* d_ws, size_t ws_size,
                              hipStream_t stream) {
    const int*   A     = (const int*)d_in[0];
    const float* x     = (const float*)d_in[1];
    const float* W     = (const float*)d_in[2];
    const float* bias  = (const float*)d_in[3];
    const float* gamma = (const float*)d_in[4];
    const float* beta  = (const float*)d_in[5];
    const int*   dil   = (const int*)d_in[6];

    float* out  = (float*)d_out;
    float* outA = out;                       // B*1*N = 524288 floats (A passthrough)
    float* outF = out + (size_t)B_ * N_;     // B*NOUT = 131072 floats (features)

    float* h  = (float*)d_ws;                // B*NOUT floats = 512 KB
    float* pS = h + (size_t)B_ * NOUT_;      // NPART*NOUT floats
    float* pQ = pS + NPART * NOUT_;          // NPART*NOUT floats

    k1_maskreduce_linear<<<B_, 512, 0, stream>>>(A, x, W, bias, dil, h, outA);
    k2_partial<<<NPART, 256, 0, stream>>>(h, pS, pQ);
    k3_norm<<<(B_ * NOUT_) / 256, 256, 0, stream>>>(h, pS, pQ, gamma, beta, outF);
}